// Round 10
// baseline (223.347 us; speedup 1.0000x reference)
//
#include <hip/hip_runtime.h>
#include <hip/hip_fp16.h>

#define FDIM 20
#define NSLOPE 0.2f
#define BSHIFT 7
#define BSIZE 128              // dst nodes per bucket
#define BCAP 4800              // slab capacity: mean 4096 + ~11 sigma
#define SCAP 4800
#define MAXBUCK 800            // >= ceil(N/128)
#define PGRID 256              // k_part blocks
#define HSTRIDE 32             // halves per padded H row (64B, line-aligned)
#define ABLK 1024              // agg block size: 16 waves, 8 lanes/dst

__device__ __forceinline__ float lrelu(float v) { return v > 0.f ? v : NSLOPE * v; }

// 1) zero bucket cursors + rank-1 layer-1 alphas; pack (alpha_src1, x) -> PX
__global__ void k_init(const float* __restrict__ x, const float* __restrict__ W1,
                       const float* __restrict__ a_src, const float* __restrict__ a_dst,
                       float2* __restrict__ PX, float* __restrict__ AD,
                       int* __restrict__ gcur, int N)
{
    int i = blockIdx.x * blockDim.x + threadIdx.x;
    if (i < MAXBUCK) gcur[i] = 0;
    if (i >= N) return;
    float cs = 0.f, cd = 0.f;
#pragma unroll
    for (int f = 0; f < FDIM; ++f) { float w = W1[f]; cs += w * a_src[f]; cd += w * a_dst[f]; }
    float xv = x[i];
    PX[i] = make_float2(xv * cs, xv);
    AD[i] = xv * cd;
}

// 2) bucket partition, block-private slab runs (R8-proven version; R9's
//    64B-aligned runs + sentinel pass REGRESSED: amp comes from partial-line
//    eviction, not line sharing).
__global__ void __launch_bounds__(1024)
k_part(const int* __restrict__ ei, int E, int nbuck,
       int* __restrict__ gcur, int* __restrict__ slab)
{
    __shared__ int hist[MAXBUCK];
    __shared__ int base[MAXBUCK];
    const int chunk = (E + PGRID - 1) / PGRID;
    const int c0 = blockIdx.x * chunk;
    const int c1 = min(c0 + chunk, E);
    for (int t = threadIdx.x; t < nbuck; t += 1024) hist[t] = 0;
    __syncthreads();
    int i = c0 + 2 * threadIdx.x;
    for (; i + 1 < c1; i += 2048) {
        int2 d2 = *(const int2*)(ei + E + i);
        atomicAdd(&hist[d2.x >> BSHIFT], 1);
        atomicAdd(&hist[d2.y >> BSHIFT], 1);
    }
    if (i < c1) atomicAdd(&hist[ei[E + i] >> BSHIFT], 1);
    __syncthreads();
    for (int t = threadIdx.x; t < nbuck; t += 1024) {
        int c = hist[t];
        base[t] = c ? atomicAdd(gcur + t, c) : 0;
        hist[t] = 0;
    }
    __syncthreads();
    i = c0 + 2 * threadIdx.x;
    for (; i + 1 < c1; i += 2048) {
        int2 s2 = *(const int2*)(ei + i);
        int2 d2 = *(const int2*)(ei + E + i);
        int bA = d2.x >> BSHIFT, bB = d2.y >> BSHIFT;
        int lpA = atomicAdd(&hist[bA], 1);
        int lpB = atomicAdd(&hist[bB], 1);
        int pA = base[bA] + lpA;
        int pB = base[bB] + lpB;
        if (pA < BCAP) slab[(size_t)bA * BCAP + pA] = (s2.x << BSHIFT) | (d2.x & (BSIZE - 1));
        if (pB < BCAP) slab[(size_t)bB * BCAP + pB] = (s2.y << BSHIFT) | (d2.y & (BSIZE - 1));
    }
    if (i < c1) {
        int s = ei[i], d = ei[E + i];
        int b = d >> BSHIFT;
        int lp = atomicAdd(&hist[b], 1);
        int pos = base[b] + lp;
        if (pos < BCAP) slab[(size_t)b * BCAP + pos] = (s << BSHIFT) | (d & (BSIZE - 1));
    }
}

// 3) layer-1 aggregate: 1024 thr, 8 lanes/dst; counting sort in LDS; register
//    accum; fused epilogue -> padded H row [20xfp16|fp32 alpha2], AD2.
//    Persists sorted lists + offsets so k_agg2 skips the sort entirely.
__global__ void __launch_bounds__(ABLK)
k_agg1(const int* __restrict__ gcur, const int* __restrict__ slab,
       const float2* __restrict__ PX, const float* __restrict__ AD,
       const float* __restrict__ W1, const float* __restrict__ b1,
       const float* __restrict__ W2,
       const float* __restrict__ as2w, const float* __restrict__ ad2w,
       __half* __restrict__ H, float* __restrict__ AD2,
       int* __restrict__ gsedge, int* __restrict__ goff, int N)
{
    __shared__ int sedge[SCAP];
    __shared__ int off[BSIZE + 1], cur[BSIZE];
    __shared__ float sAD[BSIZE];
    __shared__ float sW1[FDIM], sb1[FDIM], sW2[FDIM * FDIM], sas[FDIM], sad[FDIM];
    const int tid = threadIdx.x;
    const int b = blockIdx.x;
    const int dbase = b << BSHIFT;
    if (tid < BSIZE) { int d = dbase + tid; sAD[tid] = (d < N) ? AD[d] : 0.f; }
    for (int t = tid; t < FDIM * FDIM; t += ABLK) sW2[t] = W2[t];
    if (tid >= 960 && tid < 960 + FDIM) {
        int k = tid - 960;
        sW1[k] = W1[k]; sb1[k] = b1[k]; sas[k] = as2w[k]; sad[k] = ad2w[k];
    }
    if (tid < BSIZE + 1) off[tid] = 0;
    __syncthreads();

    const int cnt = min(gcur[b], BCAP);
    const int* sp = slab + (size_t)b * BCAP;
    for (int i = tid; i < cnt; i += ABLK)
        atomicAdd(&off[(sp[i] & (BSIZE - 1)) + 1], 1);
    __syncthreads();
    for (int o = 1; o < BSIZE; o <<= 1) {        // Hillis-Steele over off[1..128]
        int v = 0;
        if (tid < BSIZE && tid + 1 > o) v = off[tid + 1 - o];
        __syncthreads();
        if (tid < BSIZE) off[tid + 1] += v;
        __syncthreads();
    }
    if (tid < BSIZE) cur[tid] = off[tid];
    __syncthreads();
    for (int i = tid; i < cnt; i += ABLK) {
        int e = sp[i];
        int pos = atomicAdd(&cur[e & (BSIZE - 1)], 1);
        sedge[pos] = e >> BSHIFT;
    }
    __syncthreads();

    // persist sorted lists for k_agg2 (coalesced, block-private lines)
    for (int i = tid; i < cnt; i += ABLK) gsedge[(size_t)b * SCAP + i] = sedge[i];
    if (tid < BSIZE + 1) goff[b * (BSIZE + 1) + tid] = off[tid];

    const int dl = tid >> 3, sub = tid & 7;
    const float adv = sAD[dl];
    float den = 0.f, sx = 0.f;
    const int e1 = off[dl + 1];
    for (int j = off[dl] + sub; j < e1; j += 8) {
        int s = sedge[j];
        float2 p = PX[s];
        float w = __expf(lrelu(p.x + adv));
        den += w; sx += w * p.y;
    }
    den += __shfl_xor(den, 1); den += __shfl_xor(den, 2); den += __shfl_xor(den, 4);
    sx  += __shfl_xor(sx, 1);  sx  += __shfl_xor(sx, 2);  sx  += __shfl_xor(sx, 4);
    const int d = dbase + dl;
    if (sub == 0 && d < N) {
        float2 p = PX[d];                        // self-loop
        float w = __expf(lrelu(p.x + adv));
        den += w; sx += w * p.y;
        float sv = sx / (den + 1e-16f);
        float tk[FDIM];
#pragma unroll
        for (int k = 0; k < FDIM; ++k) {
            float tv = sv * sW1[k] + sb1[k];
            tk[k] = tv > 0.f ? tv : 0.f;
        }
        float pas = 0.f, pad = 0.f;
        __half2* hrow = (__half2*)(H + (size_t)d * HSTRIDE);
#pragma unroll
        for (int f = 0; f < FDIM; f += 2) {
            float h0 = 0.f, h1 = 0.f;
#pragma unroll
            for (int k = 0; k < FDIM; ++k) {
                h0 += tk[k] * sW2[k * FDIM + f];
                h1 += tk[k] * sW2[k * FDIM + f + 1];
            }
            hrow[f >> 1] = __halves2half2(__float2half(h0), __float2half(h1));
            pas += h0 * sas[f] + h1 * sas[f + 1];
            pad += h0 * sad[f] + h1 * sad[f + 1];
        }
        *(float*)(H + (size_t)d * HSTRIDE + FDIM) = pas;   // embedded alpha_src2
        AD2[d] = pad;
    }
}

// 4) layer-2 aggregate: 1024 thr, 8 lanes/dst, NO sort (tiny LDS -> full
//    occupancy); per edge 3 aligned dwordx4 loads on ONE line; fused head.
__global__ void __launch_bounds__(ABLK)
k_agg2(const int* __restrict__ gsedge, const int* __restrict__ goff,
       const __half* __restrict__ H, const float* __restrict__ AD2,
       const float* __restrict__ b2, const float* __restrict__ Wl,
       const float* __restrict__ bl,
       float* __restrict__ out, int N)
{
    __shared__ int off[BSIZE + 1];
    __shared__ float sAD[BSIZE];
    __shared__ float sb2[FDIM], sWl[FDIM];
    const int tid = threadIdx.x;
    const int b = blockIdx.x;
    const int dbase = b << BSHIFT;
    if (tid < BSIZE) { int d = dbase + tid; sAD[tid] = (d < N) ? AD2[d] : 0.f; }
    if (tid < BSIZE + 1) off[tid] = goff[b * (BSIZE + 1) + tid];
    if (tid >= 960 && tid < 960 + FDIM) {
        int k = tid - 960;
        sb2[k] = b2[k]; sWl[k] = Wl[k];
    }
    __syncthreads();

    const int* sl = gsedge + (size_t)b * SCAP;
    const int dl = tid >> 3, sub = tid & 7;
    const float adv = sAD[dl];
    float den = 0.f;
    float acc[FDIM];
#pragma unroll
    for (int k = 0; k < FDIM; ++k) acc[k] = 0.f;
    const int e1 = off[dl + 1];
    for (int j = off[dl] + sub; j < e1; j += 8) {
        int s = sl[j];
        const uint4* rp = (const uint4*)(H + (size_t)s * HSTRIDE);
        uint4 a = rp[0];                  // h0..h7
        uint4 bb = rp[1];                 // h8..h15
        uint4 c = rp[2];                  // h16..h19 | alpha_src2 | pad
        float w = __expf(lrelu(__uint_as_float(c.z) + adv));
        den += w;
        float2 f;
        f = __half22float2(*(__half2*)&a.x);  acc[0]  += w * f.x; acc[1]  += w * f.y;
        f = __half22float2(*(__half2*)&a.y);  acc[2]  += w * f.x; acc[3]  += w * f.y;
        f = __half22float2(*(__half2*)&a.z);  acc[4]  += w * f.x; acc[5]  += w * f.y;
        f = __half22float2(*(__half2*)&a.w);  acc[6]  += w * f.x; acc[7]  += w * f.y;
        f = __half22float2(*(__half2*)&bb.x); acc[8]  += w * f.x; acc[9]  += w * f.y;
        f = __half22float2(*(__half2*)&bb.y); acc[10] += w * f.x; acc[11] += w * f.y;
        f = __half22float2(*(__half2*)&bb.z); acc[12] += w * f.x; acc[13] += w * f.y;
        f = __half22float2(*(__half2*)&bb.w); acc[14] += w * f.x; acc[15] += w * f.y;
        f = __half22float2(*(__half2*)&c.x);  acc[16] += w * f.x; acc[17] += w * f.y;
        f = __half22float2(*(__half2*)&c.y);  acc[18] += w * f.x; acc[19] += w * f.y;
    }
    den += __shfl_xor(den, 1); den += __shfl_xor(den, 2); den += __shfl_xor(den, 4);
#pragma unroll
    for (int k = 0; k < FDIM; ++k) {
        acc[k] += __shfl_xor(acc[k], 1);
        acc[k] += __shfl_xor(acc[k], 2);
        acc[k] += __shfl_xor(acc[k], 4);
    }
    const int d = dbase + dl;
    if (sub == 0 && d < N) {
        const uint4* rp = (const uint4*)(H + (size_t)d * HSTRIDE);
        uint4 a = rp[0], bb = rp[1], c = rp[2];
        float w = __expf(lrelu(__uint_as_float(c.z) + adv));   // self-loop
        den += w;
        float hv[FDIM];
        float2 f;
        f = __half22float2(*(__half2*)&a.x);  hv[0]  = f.x; hv[1]  = f.y;
        f = __half22float2(*(__half2*)&a.y);  hv[2]  = f.x; hv[3]  = f.y;
        f = __half22float2(*(__half2*)&a.z);  hv[4]  = f.x; hv[5]  = f.y;
        f = __half22float2(*(__half2*)&a.w);  hv[6]  = f.x; hv[7]  = f.y;
        f = __half22float2(*(__half2*)&bb.x); hv[8]  = f.x; hv[9]  = f.y;
        f = __half22float2(*(__half2*)&bb.y); hv[10] = f.x; hv[11] = f.y;
        f = __half22float2(*(__half2*)&bb.z); hv[12] = f.x; hv[13] = f.y;
        f = __half22float2(*(__half2*)&bb.w); hv[14] = f.x; hv[15] = f.y;
        f = __half22float2(*(__half2*)&c.x);  hv[16] = f.x; hv[17] = f.y;
        f = __half22float2(*(__half2*)&c.y);  hv[18] = f.x; hv[19] = f.y;
        float inv = 1.f / (den + 1e-16f);
        float r = 0.f;
#pragma unroll
        for (int k = 0; k < FDIM; ++k) {
            float v = (acc[k] + w * hv[k]) * inv + sb2[k];
            v = v > 0.f ? v : 0.f;
            r += v * sWl[k];
        }
        out[d] = r + bl[0];
    }
}

extern "C" void kernel_launch(void* const* d_in, const int* in_sizes, int n_in,
                              void* d_out, int out_size, void* d_ws, size_t ws_size,
                              hipStream_t stream)
{
    const float* x      = (const float*)d_in[0];
    const int*   ei     = (const int*)d_in[1];
    const float* W1     = (const float*)d_in[2];
    const float* a_src1 = (const float*)d_in[3];
    const float* a_dst1 = (const float*)d_in[4];
    const float* b1     = (const float*)d_in[5];
    const float* W2     = (const float*)d_in[6];
    const float* a_src2 = (const float*)d_in[7];
    const float* a_dst2 = (const float*)d_in[8];
    const float* b2     = (const float*)d_in[9];
    const float* Wl     = (const float*)d_in[10];
    const float* bl     = (const float*)d_in[11];
    float* out = (float*)d_out;

    const int N = in_sizes[0];
    const int E = in_sizes[1] / 2;
    const int NBUCK = (N + BSIZE - 1) >> BSHIFT;    // 782 for N=100K

    // workspace layout (H first: 64B-aligned padded rows, 6.4MB)
    __half* H    = (__half*)d_ws;                   // [N*HSTRIDE]
    float2* PX   = (float2*)(H + (size_t)N * HSTRIDE); // [N] (alpha_src1, x)
    float*  AD   = (float*)(PX + N);                // [N]
    float*  AD2  = AD + N;                          // [N]
    int*  gcur   = (int*)(AD2 + N);                 // [MAXBUCK]
    int*  goff   = gcur + MAXBUCK;                  // [MAXBUCK*(BSIZE+1)]
    int*  slab   = goff + MAXBUCK * (BSIZE + 1);    // [MAXBUCK*BCAP] ~15.4MB
    int*  gsedge = slab + (size_t)MAXBUCK * BCAP;   // [MAXBUCK*SCAP] ~15.4MB

    const int nb_n = (N + 255) / 256;

    k_init<<<nb_n, 256, 0, stream>>>(x, W1, a_src1, a_dst1, PX, AD, gcur, N);
    k_part<<<PGRID, 1024, 0, stream>>>(ei, E, NBUCK, gcur, slab);
    k_agg1<<<NBUCK, ABLK, 0, stream>>>(gcur, slab, PX, AD, W1, b1, W2,
                                       a_src2, a_dst2, H, AD2, gsedge, goff, N);
    k_agg2<<<NBUCK, ABLK, 0, stream>>>(gsedge, goff, H, AD2, b2, Wl, bl, out, N);
}

// Round 11
// 207.520 us; speedup vs baseline: 1.0763x; 1.0763x over previous
//
#include <hip/hip_runtime.h>
#include <hip/hip_fp16.h>

#define FDIM 20
#define NSLOPE 0.2f
#define BSHIFT 7
#define BSIZE 128              // dst nodes per bucket
#define BCAP 7168              // slab cap incl. 16-entry/block roundup pad
#define SCAP 4800              // compact sorted-list cap (4096 + ~11 sigma)
#define MAXBUCK 800            // >= ceil(N/128)
#define PGRID 256              // k_part blocks
#define PCHUNK 12544           // LDS buffer cap >= ceil(E/PGRID)
#define HSTRIDE 32             // halves per padded H row (64B, line-aligned)
#define ABLK 512               // agg block size (R8-proven; 1024 regressed)

__device__ __forceinline__ float lrelu(float v) { return v > 0.f ? v : NSLOPE * v; }

// 1) zero bucket cursors + rank-1 layer-1 alphas; pack (alpha_src1, x) -> PX
__global__ void k_init(const float* __restrict__ x, const float* __restrict__ W1,
                       const float* __restrict__ a_src, const float* __restrict__ a_dst,
                       float2* __restrict__ PX, float* __restrict__ AD,
                       int* __restrict__ gcur, int N)
{
    int i = blockIdx.x * blockDim.x + threadIdx.x;
    if (i < MAXBUCK) gcur[i] = 0;
    if (i >= N) return;
    float cs = 0.f, cd = 0.f;
#pragma unroll
    for (int f = 0; f < FDIM; ++f) { float w = W1[f]; cs += w * a_src[f]; cd += w * a_dst[f]; }
    float xv = x[i];
    PX[i] = make_float2(xv * cs, xv);
    AD[i] = xv * cd;
}

// 2) bucket partition with LDS-staged, 64B-aligned, burst-flushed runs.
//    Whole chunk is counting-sorted in LDS, then each (block,bucket) run is
//    written as consecutive FULL cache lines exactly once (sentinel pad -1).
__global__ void __launch_bounds__(1024)
k_part(const int* __restrict__ ei, int E, int nbuck,
       int* __restrict__ gcur, int* __restrict__ slab)
{
    __shared__ int hist[MAXBUCK];    // counts -> LDS scatter cursor
    __shared__ int base[MAXBUCK];    // global aligned run base
    __shared__ int loff[MAXBUCK];    // local exclusive offset (scan result)
    __shared__ int buf[PCHUNK];      // chunk entries grouped by bucket
    const int tid = threadIdx.x;
    const int chunk = (E + PGRID - 1) / PGRID;
    const int c0 = blockIdx.x * chunk;
    const int c1 = min(c0 + chunk, E);
    for (int t = tid; t < nbuck; t += 1024) hist[t] = 0;
    __syncthreads();
    int i = c0 + 2 * tid;
    for (; i + 1 < c1; i += 2048) {
        int2 d2 = *(const int2*)(ei + E + i);
        atomicAdd(&hist[d2.x >> BSHIFT], 1);
        atomicAdd(&hist[d2.y >> BSHIFT], 1);
    }
    if (i < c1) atomicAdd(&hist[ei[E + i] >> BSHIFT], 1);
    __syncthreads();
    // reserve 64B-aligned global runs; seed scan array
    for (int t = tid; t < nbuck; t += 1024) {
        int c = hist[t];
        int r = (c + 15) & ~15;
        base[t] = r ? atomicAdd(gcur + t, r) : 0;
        loff[t] = c;
    }
    __syncthreads();
    // inclusive Hillis-Steele scan over loff[0..nbuck)
    for (int o = 1; o < nbuck; o <<= 1) {
        int v = 0;
        if (tid < nbuck && tid >= o) v = loff[tid - o];
        __syncthreads();
        if (tid < nbuck) loff[tid] += v;
        __syncthreads();
    }
    // loff -> exclusive; hist -> LDS scatter cursor (starts at exclusive)
    if (tid < nbuck) {
        int ex = loff[tid] - hist[tid];
        loff[tid] = ex;
        hist[tid] = ex;
    }
    __syncthreads();
    // scatter chunk into LDS grouped by bucket
    i = c0 + 2 * tid;
    for (; i + 1 < c1; i += 2048) {
        int2 s2 = *(const int2*)(ei + i);
        int2 d2 = *(const int2*)(ei + E + i);
        int pA = atomicAdd(&hist[d2.x >> BSHIFT], 1);
        int pB = atomicAdd(&hist[d2.y >> BSHIFT], 1);
        buf[pA] = (s2.x << BSHIFT) | (d2.x & (BSIZE - 1));
        buf[pB] = (s2.y << BSHIFT) | (d2.y & (BSIZE - 1));
    }
    if (i < c1) {
        int s = ei[i], d = ei[E + i];
        int p = atomicAdd(&hist[d >> BSHIFT], 1);
        buf[p] = (s << BSHIFT) | (d & (BSIZE - 1));
    }
    __syncthreads();
    // burst flush: one wave per bucket; full-line coalesced stores
    const int wid = tid >> 6, lane = tid & 63;
    for (int t = wid; t < nbuck; t += 16) {
        int ex = loff[t];
        int c = hist[t] - ex;                 // count placed for this bucket
        int r = (c + 15) & ~15;
        int g = base[t];
        int* dst = slab + (size_t)t * BCAP;
        for (int j = lane; j < r; j += 64) {
            int pos = g + j;
            if (pos < BCAP) dst[pos] = (j < c) ? buf[ex + j] : -1;
        }
    }
}

// 3) layer-1 aggregate (512 thr, 4 lanes/dst): counting sort skipping
//    sentinels; register accum; fused epilogue -> padded H row
//    [20xfp16|fp32 alpha2], AD2. Persists compact sorted lists for k_agg2.
__global__ void __launch_bounds__(ABLK)
k_agg1(const int* __restrict__ gcur, const int* __restrict__ slab,
       const float2* __restrict__ PX, const float* __restrict__ AD,
       const float* __restrict__ W1, const float* __restrict__ b1,
       const float* __restrict__ W2,
       const float* __restrict__ as2w, const float* __restrict__ ad2w,
       __half* __restrict__ H, float* __restrict__ AD2,
       int* __restrict__ gsedge, int* __restrict__ goff, int N)
{
    __shared__ int sedge[SCAP];
    __shared__ int off[BSIZE + 1], cur[BSIZE];
    __shared__ float sAD[BSIZE];
    __shared__ float sW1[FDIM], sb1[FDIM], sW2[FDIM * FDIM], sas[FDIM], sad[FDIM];
    const int tid = threadIdx.x;
    const int b = blockIdx.x;
    const int dbase = b << BSHIFT;
    if (tid < BSIZE) { int d = dbase + tid; sAD[tid] = (d < N) ? AD[d] : 0.f; }
    for (int t = tid; t < FDIM * FDIM; t += ABLK) sW2[t] = W2[t];
    if (tid >= 480 && tid < 480 + FDIM) {
        int k = tid - 480;
        sW1[k] = W1[k]; sb1[k] = b1[k]; sas[k] = as2w[k]; sad[k] = ad2w[k];
    }
    if (tid < BSIZE + 1) off[tid] = 0;
    __syncthreads();

    const int cnt = min(gcur[b], BCAP);
    const int* sp = slab + (size_t)b * BCAP;
    for (int i = tid; i < cnt; i += ABLK) {
        int e = sp[i];
        if (e >= 0) atomicAdd(&off[(e & (BSIZE - 1)) + 1], 1);
    }
    __syncthreads();
    for (int o = 1; o < BSIZE; o <<= 1) {        // Hillis-Steele over off[1..128]
        int v = 0;
        if (tid < BSIZE && tid + 1 > o) v = off[tid + 1 - o];
        __syncthreads();
        if (tid < BSIZE) off[tid + 1] += v;
        __syncthreads();
    }
    if (tid < BSIZE) cur[tid] = off[tid];
    __syncthreads();
    for (int i = tid; i < cnt; i += ABLK) {
        int e = sp[i];
        if (e >= 0) {
            int pos = atomicAdd(&cur[e & (BSIZE - 1)], 1);
            sedge[pos] = e >> BSHIFT;
        }
    }
    __syncthreads();

    // persist compact sorted lists for k_agg2
    const int cntT = off[BSIZE];
    for (int i = tid; i < cntT; i += ABLK) gsedge[(size_t)b * SCAP + i] = sedge[i];
    if (tid < BSIZE + 1) goff[b * (BSIZE + 1) + tid] = off[tid];

    const int dl = tid >> 2, sub = tid & 3;
    const float adv = sAD[dl];
    float den = 0.f, sx = 0.f;
    const int e1 = off[dl + 1];
#pragma unroll 2
    for (int j = off[dl] + sub; j < e1; j += 4) {
        int s = sedge[j];
        float2 p = PX[s];
        float w = __expf(lrelu(p.x + adv));
        den += w; sx += w * p.y;
    }
    den += __shfl_xor(den, 1); den += __shfl_xor(den, 2);
    sx  += __shfl_xor(sx, 1);  sx  += __shfl_xor(sx, 2);
    const int d = dbase + dl;
    if (sub == 0 && d < N) {
        float2 p = PX[d];                        // self-loop
        float w = __expf(lrelu(p.x + adv));
        den += w; sx += w * p.y;
        float sv = sx / (den + 1e-16f);
        float tk[FDIM];
#pragma unroll
        for (int k = 0; k < FDIM; ++k) {
            float tv = sv * sW1[k] + sb1[k];
            tk[k] = tv > 0.f ? tv : 0.f;
        }
        float pas = 0.f, pad = 0.f;
        __half2* hrow = (__half2*)(H + (size_t)d * HSTRIDE);
#pragma unroll
        for (int f = 0; f < FDIM; f += 2) {
            float h0 = 0.f, h1 = 0.f;
#pragma unroll
            for (int k = 0; k < FDIM; ++k) {
                h0 += tk[k] * sW2[k * FDIM + f];
                h1 += tk[k] * sW2[k * FDIM + f + 1];
            }
            hrow[f >> 1] = __halves2half2(__float2half(h0), __float2half(h1));
            pas += h0 * sas[f] + h1 * sas[f + 1];
            pad += h0 * sad[f] + h1 * sad[f + 1];
        }
        *(float*)(H + (size_t)d * HSTRIDE + FDIM) = pas;   // embedded alpha_src2
        AD2[d] = pad;
    }
}

// 4) layer-2 aggregate (512 thr, 4 lanes/dst): NO sort, streams compact
//    lists; per edge 3 aligned dwordx4 loads on ONE line; fused head -> out.
__global__ void __launch_bounds__(ABLK)
k_agg2(const int* __restrict__ gsedge, const int* __restrict__ goff,
       const __half* __restrict__ H, const float* __restrict__ AD2,
       const float* __restrict__ b2, const float* __restrict__ Wl,
       const float* __restrict__ bl,
       float* __restrict__ out, int N)
{
    __shared__ int off[BSIZE + 1];
    __shared__ float sAD[BSIZE];
    __shared__ float sb2[FDIM], sWl[FDIM];
    const int tid = threadIdx.x;
    const int b = blockIdx.x;
    const int dbase = b << BSHIFT;
    if (tid < BSIZE) { int d = dbase + tid; sAD[tid] = (d < N) ? AD2[d] : 0.f; }
    if (tid < BSIZE + 1) off[tid] = goff[b * (BSIZE + 1) + tid];
    if (tid >= 480 && tid < 480 + FDIM) {
        int k = tid - 480;
        sb2[k] = b2[k]; sWl[k] = Wl[k];
    }
    __syncthreads();

    const int* sl = gsedge + (size_t)b * SCAP;
    const int dl = tid >> 2, sub = tid & 3;
    const float adv = sAD[dl];
    float den = 0.f;
    float acc[FDIM];
#pragma unroll
    for (int k = 0; k < FDIM; ++k) acc[k] = 0.f;
    const int e1 = off[dl + 1];
#pragma unroll 2
    for (int j = off[dl] + sub; j < e1; j += 4) {
        int s = sl[j];
        const uint4* rp = (const uint4*)(H + (size_t)s * HSTRIDE);
        uint4 a = rp[0];                  // h0..h7
        uint4 bb = rp[1];                 // h8..h15
        uint4 c = rp[2];                  // h16..h19 | alpha_src2 | pad
        float w = __expf(lrelu(__uint_as_float(c.z) + adv));
        den += w;
        float2 f;
        f = __half22float2(*(__half2*)&a.x);  acc[0]  += w * f.x; acc[1]  += w * f.y;
        f = __half22float2(*(__half2*)&a.y);  acc[2]  += w * f.x; acc[3]  += w * f.y;
        f = __half22float2(*(__half2*)&a.z);  acc[4]  += w * f.x; acc[5]  += w * f.y;
        f = __half22float2(*(__half2*)&a.w);  acc[6]  += w * f.x; acc[7]  += w * f.y;
        f = __half22float2(*(__half2*)&bb.x); acc[8]  += w * f.x; acc[9]  += w * f.y;
        f = __half22float2(*(__half2*)&bb.y); acc[10] += w * f.x; acc[11] += w * f.y;
        f = __half22float2(*(__half2*)&bb.z); acc[12] += w * f.x; acc[13] += w * f.y;
        f = __half22float2(*(__half2*)&bb.w); acc[14] += w * f.x; acc[15] += w * f.y;
        f = __half22float2(*(__half2*)&c.x);  acc[16] += w * f.x; acc[17] += w * f.y;
        f = __half22float2(*(__half2*)&c.y);  acc[18] += w * f.x; acc[19] += w * f.y;
    }
    den += __shfl_xor(den, 1); den += __shfl_xor(den, 2);
#pragma unroll
    for (int k = 0; k < FDIM; ++k) {
        acc[k] += __shfl_xor(acc[k], 1);
        acc[k] += __shfl_xor(acc[k], 2);
    }
    const int d = dbase + dl;
    if (sub == 0 && d < N) {
        const uint4* rp = (const uint4*)(H + (size_t)d * HSTRIDE);
        uint4 a = rp[0], bb = rp[1], c = rp[2];
        float w = __expf(lrelu(__uint_as_float(c.z) + adv));   // self-loop
        den += w;
        float hv[FDIM];
        float2 f;
        f = __half22float2(*(__half2*)&a.x);  hv[0]  = f.x; hv[1]  = f.y;
        f = __half22float2(*(__half2*)&a.y);  hv[2]  = f.x; hv[3]  = f.y;
        f = __half22float2(*(__half2*)&a.z);  hv[4]  = f.x; hv[5]  = f.y;
        f = __half22float2(*(__half2*)&a.w);  hv[6]  = f.x; hv[7]  = f.y;
        f = __half22float2(*(__half2*)&bb.x); hv[8]  = f.x; hv[9]  = f.y;
        f = __half22float2(*(__half2*)&bb.y); hv[10] = f.x; hv[11] = f.y;
        f = __half22float2(*(__half2*)&bb.z); hv[12] = f.x; hv[13] = f.y;
        f = __half22float2(*(__half2*)&bb.w); hv[14] = f.x; hv[15] = f.y;
        f = __half22float2(*(__half2*)&c.x);  hv[16] = f.x; hv[17] = f.y;
        f = __half22float2(*(__half2*)&c.y);  hv[18] = f.x; hv[19] = f.y;
        float inv = 1.f / (den + 1e-16f);
        float r = 0.f;
#pragma unroll
        for (int k = 0; k < FDIM; ++k) {
            float v = (acc[k] + w * hv[k]) * inv + sb2[k];
            v = v > 0.f ? v : 0.f;
            r += v * sWl[k];
        }
        out[d] = r + bl[0];
    }
}

extern "C" void kernel_launch(void* const* d_in, const int* in_sizes, int n_in,
                              void* d_out, int out_size, void* d_ws, size_t ws_size,
                              hipStream_t stream)
{
    const float* x      = (const float*)d_in[0];
    const int*   ei     = (const int*)d_in[1];
    const float* W1     = (const float*)d_in[2];
    const float* a_src1 = (const float*)d_in[3];
    const float* a_dst1 = (const float*)d_in[4];
    const float* b1     = (const float*)d_in[5];
    const float* W2     = (const float*)d_in[6];
    const float* a_src2 = (const float*)d_in[7];
    const float* a_dst2 = (const float*)d_in[8];
    const float* b2     = (const float*)d_in[9];
    const float* Wl     = (const float*)d_in[10];
    const float* bl     = (const float*)d_in[11];
    float* out = (float*)d_out;

    const int N = in_sizes[0];
    const int E = in_sizes[1] / 2;
    const int NBUCK = (N + BSIZE - 1) >> BSHIFT;    // 782 for N=100K

    // workspace layout (H first: 64B-aligned padded rows, 6.4MB)
    __half* H    = (__half*)d_ws;                   // [N*HSTRIDE]
    float2* PX   = (float2*)(H + (size_t)N * HSTRIDE); // [N] (alpha_src1, x)
    float*  AD   = (float*)(PX + N);                // [N]
    float*  AD2  = AD + N;                          // [N]
    int*  gcur   = (int*)(AD2 + N);                 // [MAXBUCK]
    int*  goff   = gcur + MAXBUCK;                  // [MAXBUCK*(BSIZE+1)]
    int*  slab   = goff + MAXBUCK * (BSIZE + 1);    // [MAXBUCK*BCAP] ~22.9MB
    int*  gsedge = slab + (size_t)MAXBUCK * BCAP;   // [MAXBUCK*SCAP] ~15.4MB

    const int nb_n = (N + 255) / 256;

    k_init<<<nb_n, 256, 0, stream>>>(x, W1, a_src1, a_dst1, PX, AD, gcur, N);
    k_part<<<PGRID, 1024, 0, stream>>>(ei, E, NBUCK, gcur, slab);
    k_agg1<<<NBUCK, ABLK, 0, stream>>>(gcur, slab, PX, AD, W1, b1, W2,
                                       a_src2, a_dst2, H, AD2, gsedge, goff, N);
    k_agg2<<<NBUCK, ABLK, 0, stream>>>(gsedge, goff, H, AD2, b2, Wl, bl, out, N);
}

// Round 12
// 201.391 us; speedup vs baseline: 1.1090x; 1.0304x over previous
//
#include <hip/hip_runtime.h>
#include <hip/hip_fp16.h>

#define FDIM 20
#define NSLOPE 0.2f
#define BSHIFT 7
#define BSIZE 128              // dst nodes per bucket
#define BCAP 7168              // slab cap incl. 16-entry/block roundup pad
#define SCAP 4800              // compact sorted-list cap (4096 + ~11 sigma)
#define MAXBUCK 800            // >= ceil(N/128)
#define PGRID 256              // k_part blocks
#define PCHUNK 12544           // LDS buffer cap >= ceil(E/PGRID)
#define HSTRIDE 32             // halves per padded H row (64B, line-aligned)
#define ABLK 512               // agg1 block size

__device__ __forceinline__ float lrelu(float v) { return v > 0.f ? v : NSLOPE * v; }

// 1) zero bucket cursors + rank-1 layer-1 alphas; pack (alpha_src1, x) -> PX
__global__ void k_init(const float* __restrict__ x, const float* __restrict__ W1,
                       const float* __restrict__ a_src, const float* __restrict__ a_dst,
                       float2* __restrict__ PX, float* __restrict__ AD,
                       int* __restrict__ gcur, int N)
{
    int i = blockIdx.x * blockDim.x + threadIdx.x;
    if (i < MAXBUCK) gcur[i] = 0;
    if (i >= N) return;
    float cs = 0.f, cd = 0.f;
#pragma unroll
    for (int f = 0; f < FDIM; ++f) { float w = W1[f]; cs += w * a_src[f]; cd += w * a_dst[f]; }
    float xv = x[i];
    PX[i] = make_float2(xv * cs, xv);
    AD[i] = xv * cd;
}

// 2) bucket partition with LDS-staged, 64B-aligned, burst-flushed runs
//    (R11-proven: slab lines written whole, exactly once).
__global__ void __launch_bounds__(1024)
k_part(const int* __restrict__ ei, int E, int nbuck,
       int* __restrict__ gcur, int* __restrict__ slab)
{
    __shared__ int hist[MAXBUCK];    // counts -> LDS scatter cursor
    __shared__ int base[MAXBUCK];    // global aligned run base
    __shared__ int loff[MAXBUCK];    // local exclusive offset (scan result)
    __shared__ int buf[PCHUNK];      // chunk entries grouped by bucket
    const int tid = threadIdx.x;
    const int chunk = (E + PGRID - 1) / PGRID;
    const int c0 = blockIdx.x * chunk;
    const int c1 = min(c0 + chunk, E);
    for (int t = tid; t < nbuck; t += 1024) hist[t] = 0;
    __syncthreads();
    int i = c0 + 2 * tid;
    for (; i + 1 < c1; i += 2048) {
        int2 d2 = *(const int2*)(ei + E + i);
        atomicAdd(&hist[d2.x >> BSHIFT], 1);
        atomicAdd(&hist[d2.y >> BSHIFT], 1);
    }
    if (i < c1) atomicAdd(&hist[ei[E + i] >> BSHIFT], 1);
    __syncthreads();
    for (int t = tid; t < nbuck; t += 1024) {
        int c = hist[t];
        int r = (c + 15) & ~15;
        base[t] = r ? atomicAdd(gcur + t, r) : 0;
        loff[t] = c;
    }
    __syncthreads();
    for (int o = 1; o < nbuck; o <<= 1) {
        int v = 0;
        if (tid < nbuck && tid >= o) v = loff[tid - o];
        __syncthreads();
        if (tid < nbuck) loff[tid] += v;
        __syncthreads();
    }
    if (tid < nbuck) {
        int ex = loff[tid] - hist[tid];
        loff[tid] = ex;
        hist[tid] = ex;
    }
    __syncthreads();
    i = c0 + 2 * tid;
    for (; i + 1 < c1; i += 2048) {
        int2 s2 = *(const int2*)(ei + i);
        int2 d2 = *(const int2*)(ei + E + i);
        int pA = atomicAdd(&hist[d2.x >> BSHIFT], 1);
        int pB = atomicAdd(&hist[d2.y >> BSHIFT], 1);
        buf[pA] = (s2.x << BSHIFT) | (d2.x & (BSIZE - 1));
        buf[pB] = (s2.y << BSHIFT) | (d2.y & (BSIZE - 1));
    }
    if (i < c1) {
        int s = ei[i], d = ei[E + i];
        int p = atomicAdd(&hist[d >> BSHIFT], 1);
        buf[p] = (s << BSHIFT) | (d & (BSIZE - 1));
    }
    __syncthreads();
    const int wid = tid >> 6, lane = tid & 63;
    for (int t = wid; t < nbuck; t += 16) {
        int ex = loff[t];
        int c = hist[t] - ex;
        int r = (c + 15) & ~15;
        int g = base[t];
        int* dst = slab + (size_t)t * BCAP;
        for (int j = lane; j < r; j += 64) {
            int pos = g + j;
            if (pos < BCAP) dst[pos] = (j < c) ? buf[ex + j] : -1;
        }
    }
}

// 3) layer-1 aggregate (512 thr, 4 lanes/dst): counting sort skipping
//    sentinels; register accum; fused epilogue -> padded H row
//    [20xfp16|fp32 alpha2], AD2. Persists compact sorted lists for k_agg2.
__global__ void __launch_bounds__(ABLK)
k_agg1(const int* __restrict__ gcur, const int* __restrict__ slab,
       const float2* __restrict__ PX, const float* __restrict__ AD,
       const float* __restrict__ W1, const float* __restrict__ b1,
       const float* __restrict__ W2,
       const float* __restrict__ as2w, const float* __restrict__ ad2w,
       __half* __restrict__ H, float* __restrict__ AD2,
       int* __restrict__ gsedge, int* __restrict__ goff, int N)
{
    __shared__ int sedge[SCAP];
    __shared__ int off[BSIZE + 1], cur[BSIZE];
    __shared__ float sAD[BSIZE];
    __shared__ float sW1[FDIM], sb1[FDIM], sW2[FDIM * FDIM], sas[FDIM], sad[FDIM];
    const int tid = threadIdx.x;
    const int b = blockIdx.x;
    const int dbase = b << BSHIFT;
    if (tid < BSIZE) { int d = dbase + tid; sAD[tid] = (d < N) ? AD[d] : 0.f; }
    for (int t = tid; t < FDIM * FDIM; t += ABLK) sW2[t] = W2[t];
    if (tid >= 480 && tid < 480 + FDIM) {
        int k = tid - 480;
        sW1[k] = W1[k]; sb1[k] = b1[k]; sas[k] = as2w[k]; sad[k] = ad2w[k];
    }
    if (tid < BSIZE + 1) off[tid] = 0;
    __syncthreads();

    const int cnt = min(gcur[b], BCAP);
    const int* sp = slab + (size_t)b * BCAP;
    for (int i = tid; i < cnt; i += ABLK) {
        int e = sp[i];
        if (e >= 0) atomicAdd(&off[(e & (BSIZE - 1)) + 1], 1);
    }
    __syncthreads();
    for (int o = 1; o < BSIZE; o <<= 1) {        // Hillis-Steele over off[1..128]
        int v = 0;
        if (tid < BSIZE && tid + 1 > o) v = off[tid + 1 - o];
        __syncthreads();
        if (tid < BSIZE) off[tid + 1] += v;
        __syncthreads();
    }
    if (tid < BSIZE) cur[tid] = off[tid];
    __syncthreads();
    for (int i = tid; i < cnt; i += ABLK) {
        int e = sp[i];
        if (e >= 0) {
            int pos = atomicAdd(&cur[e & (BSIZE - 1)], 1);
            sedge[pos] = e >> BSHIFT;
        }
    }
    __syncthreads();

    // persist compact sorted lists for k_agg2
    const int cntT = off[BSIZE];
    for (int i = tid; i < cntT; i += ABLK) gsedge[(size_t)b * SCAP + i] = sedge[i];
    if (tid < BSIZE + 1) goff[b * (BSIZE + 1) + tid] = off[tid];

    const int dl = tid >> 2, sub = tid & 3;
    const float adv = sAD[dl];
    float den = 0.f, sx = 0.f;
    const int e1 = off[dl + 1];
#pragma unroll 2
    for (int j = off[dl] + sub; j < e1; j += 4) {
        int s = sedge[j];
        float2 p = PX[s];
        float w = __expf(lrelu(p.x + adv));
        den += w; sx += w * p.y;
    }
    den += __shfl_xor(den, 1); den += __shfl_xor(den, 2);
    sx  += __shfl_xor(sx, 1);  sx  += __shfl_xor(sx, 2);
    const int d = dbase + dl;
    if (sub == 0 && d < N) {
        float2 p = PX[d];                        // self-loop
        float w = __expf(lrelu(p.x + adv));
        den += w; sx += w * p.y;
        float sv = sx / (den + 1e-16f);
        float tk[FDIM];
#pragma unroll
        for (int k = 0; k < FDIM; ++k) {
            float tv = sv * sW1[k] + sb1[k];
            tk[k] = tv > 0.f ? tv : 0.f;
        }
        float pas = 0.f, pad = 0.f;
        __half2* hrow = (__half2*)(H + (size_t)d * HSTRIDE);
#pragma unroll
        for (int f = 0; f < FDIM; f += 2) {
            float h0 = 0.f, h1 = 0.f;
#pragma unroll
            for (int k = 0; k < FDIM; ++k) {
                h0 += tk[k] * sW2[k * FDIM + f];
                h1 += tk[k] * sW2[k * FDIM + f + 1];
            }
            hrow[f >> 1] = __halves2half2(__float2half(h0), __float2half(h1));
            pas += h0 * sas[f] + h1 * sas[f + 1];
            pad += h0 * sad[f] + h1 * sad[f + 1];
        }
        *(float*)(H + (size_t)d * HSTRIDE + FDIM) = pas;   // embedded alpha_src2
        AD2[d] = pad;
    }
}

// 4) layer-2 aggregate: HALF-bucket blocks (256 thr, 64 dsts, 4 lanes/dst)
//    for 2x block count -> finer CU packing / higher resident-wave count.
//    NO sort (streams agg1's compact lists); 3 aligned dwordx4 loads per
//    edge on ONE line; fused final head -> out.
__global__ void __launch_bounds__(256)
k_agg2(const int* __restrict__ gsedge, const int* __restrict__ goff,
       const __half* __restrict__ H, const float* __restrict__ AD2,
       const float* __restrict__ b2, const float* __restrict__ Wl,
       const float* __restrict__ bl,
       float* __restrict__ out, int N)
{
    __shared__ int off[65];
    __shared__ float sAD[64];
    __shared__ float sb2[FDIM], sWl[FDIM];
    const int tid = threadIdx.x;
    const int b = blockIdx.x >> 1;           // parent bucket
    const int half = blockIdx.x & 1;         // which 64-dst half
    const int dbase = (b << BSHIFT) + (half << 6);
    if (tid < 64) { int d = dbase + tid; sAD[tid] = (d < N) ? AD2[d] : 0.f; }
    if (tid < 65) off[tid] = goff[b * (BSIZE + 1) + (half << 6) + tid];
    if (tid >= 224 && tid < 224 + FDIM) {
        int k = tid - 224;
        sb2[k] = b2[k]; sWl[k] = Wl[k];
    }
    __syncthreads();

    const int* sl = gsedge + (size_t)b * SCAP;
    const int dl = tid >> 2, sub = tid & 3;
    const float adv = sAD[dl];
    float den = 0.f;
    float acc[FDIM];
#pragma unroll
    for (int k = 0; k < FDIM; ++k) acc[k] = 0.f;
    const int e1 = off[dl + 1];
#pragma unroll 2
    for (int j = off[dl] + sub; j < e1; j += 4) {
        int s = sl[j];
        const uint4* rp = (const uint4*)(H + (size_t)s * HSTRIDE);
        uint4 a = rp[0];                  // h0..h7
        uint4 bb = rp[1];                 // h8..h15
        uint4 c = rp[2];                  // h16..h19 | alpha_src2 | pad
        float w = __expf(lrelu(__uint_as_float(c.z) + adv));
        den += w;
        float2 f;
        f = __half22float2(*(__half2*)&a.x);  acc[0]  += w * f.x; acc[1]  += w * f.y;
        f = __half22float2(*(__half2*)&a.y);  acc[2]  += w * f.x; acc[3]  += w * f.y;
        f = __half22float2(*(__half2*)&a.z);  acc[4]  += w * f.x; acc[5]  += w * f.y;
        f = __half22float2(*(__half2*)&a.w);  acc[6]  += w * f.x; acc[7]  += w * f.y;
        f = __half22float2(*(__half2*)&bb.x); acc[8]  += w * f.x; acc[9]  += w * f.y;
        f = __half22float2(*(__half2*)&bb.y); acc[10] += w * f.x; acc[11] += w * f.y;
        f = __half22float2(*(__half2*)&bb.z); acc[12] += w * f.x; acc[13] += w * f.y;
        f = __half22float2(*(__half2*)&bb.w); acc[14] += w * f.x; acc[15] += w * f.y;
        f = __half22float2(*(__half2*)&c.x);  acc[16] += w * f.x; acc[17] += w * f.y;
        f = __half22float2(*(__half2*)&c.y);  acc[18] += w * f.x; acc[19] += w * f.y;
    }
    den += __shfl_xor(den, 1); den += __shfl_xor(den, 2);
#pragma unroll
    for (int k = 0; k < FDIM; ++k) {
        acc[k] += __shfl_xor(acc[k], 1);
        acc[k] += __shfl_xor(acc[k], 2);
    }
    const int d = dbase + dl;
    if (sub == 0 && d < N) {
        const uint4* rp = (const uint4*)(H + (size_t)d * HSTRIDE);
        uint4 a = rp[0], bb = rp[1], c = rp[2];
        float w = __expf(lrelu(__uint_as_float(c.z) + adv));   // self-loop
        den += w;
        float hv[FDIM];
        float2 f;
        f = __half22float2(*(__half2*)&a.x);  hv[0]  = f.x; hv[1]  = f.y;
        f = __half22float2(*(__half2*)&a.y);  hv[2]  = f.x; hv[3]  = f.y;
        f = __half22float2(*(__half2*)&a.z);  hv[4]  = f.x; hv[5]  = f.y;
        f = __half22float2(*(__half2*)&a.w);  hv[6]  = f.x; hv[7]  = f.y;
        f = __half22float2(*(__half2*)&bb.x); hv[8]  = f.x; hv[9]  = f.y;
        f = __half22float2(*(__half2*)&bb.y); hv[10] = f.x; hv[11] = f.y;
        f = __half22float2(*(__half2*)&bb.z); hv[12] = f.x; hv[13] = f.y;
        f = __half22float2(*(__half2*)&bb.w); hv[14] = f.x; hv[15] = f.y;
        f = __half22float2(*(__half2*)&c.x);  hv[16] = f.x; hv[17] = f.y;
        f = __half22float2(*(__half2*)&c.y);  hv[18] = f.x; hv[19] = f.y;
        float inv = 1.f / (den + 1e-16f);
        float r = 0.f;
#pragma unroll
        for (int k = 0; k < FDIM; ++k) {
            float v = (acc[k] + w * hv[k]) * inv + sb2[k];
            v = v > 0.f ? v : 0.f;
            r += v * sWl[k];
        }
        out[d] = r + bl[0];
    }
}

extern "C" void kernel_launch(void* const* d_in, const int* in_sizes, int n_in,
                              void* d_out, int out_size, void* d_ws, size_t ws_size,
                              hipStream_t stream)
{
    const float* x      = (const float*)d_in[0];
    const int*   ei     = (const int*)d_in[1];
    const float* W1     = (const float*)d_in[2];
    const float* a_src1 = (const float*)d_in[3];
    const float* a_dst1 = (const float*)d_in[4];
    const float* b1     = (const float*)d_in[5];
    const float* W2     = (const float*)d_in[6];
    const float* a_src2 = (const float*)d_in[7];
    const float* a_dst2 = (const float*)d_in[8];
    const float* b2     = (const float*)d_in[9];
    const float* Wl     = (const float*)d_in[10];
    const float* bl     = (const float*)d_in[11];
    float* out = (float*)d_out;

    const int N = in_sizes[0];
    const int E = in_sizes[1] / 2;
    const int NBUCK = (N + BSIZE - 1) >> BSHIFT;    // 782 for N=100K

    // workspace layout (H first: 64B-aligned padded rows, 6.4MB)
    __half* H    = (__half*)d_ws;                   // [N*HSTRIDE]
    float2* PX   = (float2*)(H + (size_t)N * HSTRIDE); // [N] (alpha_src1, x)
    float*  AD   = (float*)(PX + N);                // [N]
    float*  AD2  = AD + N;                          // [N]
    int*  gcur   = (int*)(AD2 + N);                 // [MAXBUCK]
    int*  goff   = gcur + MAXBUCK;                  // [MAXBUCK*(BSIZE+1)]
    int*  slab   = goff + MAXBUCK * (BSIZE + 1);    // [MAXBUCK*BCAP] ~22.9MB
    int*  gsedge = slab + (size_t)MAXBUCK * BCAP;   // [MAXBUCK*SCAP] ~15.4MB

    const int nb_n = (N + 255) / 256;

    k_init<<<nb_n, 256, 0, stream>>>(x, W1, a_src1, a_dst1, PX, AD, gcur, N);
    k_part<<<PGRID, 1024, 0, stream>>>(ei, E, NBUCK, gcur, slab);
    k_agg1<<<NBUCK, ABLK, 0, stream>>>(gcur, slab, PX, AD, W1, b1, W2,
                                       a_src2, a_dst2, H, AD2, gsedge, goff, N);
    k_agg2<<<2 * NBUCK, 256, 0, stream>>>(gsedge, goff, H, AD2, b2, Wl, bl, out, N);
}